// Round 3
// baseline (24.540 us; speedup 1.0000x reference)
//
#include <hip/hip_runtime.h>

// BatchedFoveator: out[b,t,c,i,j] = mean of img[b,c, cy+s*i : +s, cx+s*j : +s]
// B=32, C=3, IMG=512, NT=160 tokens (64 @s=1, 48 @s=2, 48 @s=4), 16x16 px/token.
// 4 outputs (consecutive j) per thread -> all-float4 I/O; nontemporal stores.

#define NTOK    160
#define NB      32
#define NC      3

typedef float fvec4 __attribute__((ext_vector_type(4)));  // native vector for nt-store

// Decode token index -> (corner_x, corner_y, stride). Matches the reference's
// _precompute_tokens(): level 0 = full 8x8 grid (s=1, corner 192+16*{j,i});
// levels 1,2 = 8x8 grid minus central 4x4 ring, enumerated rows 0-1 full,
// rows 2-5 cols {0,1,6,7}, rows 6-7 full.
__device__ __forceinline__ void token_params(int t, int& cx, int& cy, int& s) {
    if (t < 64) {
        int i = t >> 3, j = t & 7;
        cx = 192 + 16 * j;
        cy = 192 + 16 * i;
        s = 1;
    } else {
        int u = t - 64;
        bool lvl2 = (u >= 48);
        if (lvl2) u -= 48;
        int i, j;
        if (u < 16) {              // rows 0,1 full
            i = u >> 3; j = u & 7;
        } else if (u < 32) {       // rows 2..5, cols 0,1,6,7
            int v = u - 16;
            i = 2 + (v >> 2);
            int p = v & 3;
            j = (p < 2) ? p : (p + 4);
        } else {                   // rows 6,7 full
            int v = u - 32;
            i = 6 + (v >> 3); j = v & 7;
        }
        if (!lvl2) { cx = 128 + 32 * j; cy = 128 + 32 * i; s = 2; }
        else       { cx = 64 * j;       cy = 64 * i;       s = 4; }
    }
}

__global__ __launch_bounds__(256) void fovea_kernel(const float* __restrict__ img,
                                                    fvec4* __restrict__ out) {
    int o = blockIdx.x * 256 + threadIdx.x;   // out4 index
    // o = ((((b*NTOK + t)*NC + c)*16 + i)*4 + j4);  j = 4*j4 + k
    int j4 = o & 3;
    int i  = (o >> 2) & 15;
    int c  = (o >> 6) % NC;
    int bt = o / (NC * 64);
    int t  = bt % NTOK;
    int b  = bt / NTOK;

    int cx, cy, s;
    token_params(t, cx, cy, s);

    const float* base = img + ((size_t)(b * NC + c) << 18);  // 512*512 = 1<<18

    fvec4 r;
    if (s == 1) {
        int y0 = cy + i, x0 = cx + 4 * j4;
        r = *reinterpret_cast<const fvec4*>(base + ((size_t)y0 << 9) + x0);
    } else if (s == 2) {
        int y0 = cy + 2 * i, x0 = cx + 8 * j4;
        const fvec4* p0 = reinterpret_cast<const fvec4*>(base + ((size_t)y0 << 9) + x0);
        const fvec4* p1 = reinterpret_cast<const fvec4*>(base + ((size_t)(y0 + 1) << 9) + x0);
        fvec4 a0 = p0[0], a1 = p0[1];
        fvec4 b0 = p1[0], b1 = p1[1];
        r.x = (a0.x + a0.y + b0.x + b0.y) * 0.25f;
        r.y = (a0.z + a0.w + b0.z + b0.w) * 0.25f;
        r.z = (a1.x + a1.y + b1.x + b1.y) * 0.25f;
        r.w = (a1.z + a1.w + b1.z + b1.w) * 0.25f;
    } else {
        int y0 = cy + 4 * i, x0 = cx + 16 * j4;
        float s0 = 0.f, s1 = 0.f, s2 = 0.f, s3 = 0.f;
        #pragma unroll
        for (int dy = 0; dy < 4; ++dy) {
            const fvec4* p = reinterpret_cast<const fvec4*>(base + ((size_t)(y0 + dy) << 9) + x0);
            fvec4 v0 = p[0], v1 = p[1], v2 = p[2], v3 = p[3];
            s0 += v0.x + v0.y + v0.z + v0.w;
            s1 += v1.x + v1.y + v1.z + v1.w;
            s2 += v2.x + v2.y + v2.z + v2.w;
            s3 += v3.x + v3.y + v3.z + v3.w;
        }
        r.x = s0 * 0.0625f; r.y = s1 * 0.0625f;
        r.z = s2 * 0.0625f; r.w = s3 * 0.0625f;
    }
    __builtin_nontemporal_store(r, out + o);
}

extern "C" void kernel_launch(void* const* d_in, const int* in_sizes, int n_in,
                              void* d_out, int out_size, void* d_ws, size_t ws_size,
                              hipStream_t stream) {
    const float* img = (const float*)d_in[0];
    fvec4* out = (fvec4*)d_out;
    // out_size = 32*160*3*16*16 = 3,932,160 floats -> 983,040 float4
    int total4 = NB * NTOK * NC * 16 * 4;
    int blocks = total4 / 256;  // 3840
    fovea_kernel<<<blocks, 256, 0, stream>>>(img, out);
}

// Round 4
// 21.991 us; speedup vs baseline: 1.1159x; 1.1159x over previous
//
#include <hip/hip_runtime.h>

// BatchedFoveator: out[b,t,c,i,j] = mean of img[b,c, cy+s*i : +s, cx+s*j : +s]
// B=32, C=3, IMG=512, NT=160 tokens (64 @s=1, 48 @s=2, 48 @s=4), 16x16 px/token.
// One output/thread; j lane-minor -> 16-lane contiguous load runs on every path
// (s=1: 64B, s=2: 128B via float2, s=4: 256B via float4), 1KiB contiguous stores.

#define IMG     512
#define NTOK    160
#define NB      32
#define NC      3

// Decode token index -> (corner_x, corner_y, stride). Matches the reference's
// _precompute_tokens(): level 0 = full 8x8 grid (s=1, corner 192+16*{j,i});
// levels 1,2 = 8x8 grid minus central 4x4 ring, enumerated rows 0-1 full,
// rows 2-5 cols {0,1,6,7}, rows 6-7 full.
__device__ __forceinline__ void token_params(int t, int& cx, int& cy, int& s) {
    if (t < 64) {
        int i = t >> 3, j = t & 7;
        cx = 192 + 16 * j;
        cy = 192 + 16 * i;
        s = 1;
    } else {
        int u = t - 64;
        bool lvl2 = (u >= 48);
        if (lvl2) u -= 48;
        int i, j;
        if (u < 16) {              // rows 0,1 full
            i = u >> 3; j = u & 7;
        } else if (u < 32) {       // rows 2..5, cols 0,1,6,7
            int v = u - 16;
            i = 2 + (v >> 2);
            int p = v & 3;
            j = (p < 2) ? p : (p + 4);
        } else {                   // rows 6,7 full
            int v = u - 32;
            i = 6 + (v >> 3); j = v & 7;
        }
        if (!lvl2) { cx = 128 + 32 * j; cy = 128 + 32 * i; s = 2; }
        else       { cx = 64 * j;       cy = 64 * i;       s = 4; }
    }
}

__global__ __launch_bounds__(256) void fovea_kernel(const float* __restrict__ img,
                                                    float* __restrict__ out) {
    int idx = blockIdx.x * 256 + threadIdx.x;
    // idx = (((b*NTOK + t)*NC + c)*16 + i)*16 + j
    int j  = idx & 15;
    int i  = (idx >> 4) & 15;
    int c  = (idx >> 8) % NC;
    int bt = idx / (NC * 256);
    int t  = bt % NTOK;
    int b  = bt / NTOK;

    int cx, cy, s;
    token_params(t, cx, cy, s);

    const float* base = img + ((size_t)(b * NC + c) << 18);  // 512*512 = 1<<18
    int x0 = cx + s * j;
    int y0 = cy + s * i;

    float sum;
    if (s == 1) {
        sum = base[(y0 << 9) + x0];
    } else if (s == 2) {
        sum = 0.f;
        #pragma unroll
        for (int dy = 0; dy < 2; ++dy) {
            const float2 v = *reinterpret_cast<const float2*>(base + ((size_t)(y0 + dy) << 9) + x0);
            sum += v.x + v.y;
        }
        sum *= 0.25f;
    } else {
        sum = 0.f;
        #pragma unroll
        for (int dy = 0; dy < 4; ++dy) {
            const float4 v = *reinterpret_cast<const float4*>(base + ((size_t)(y0 + dy) << 9) + x0);
            sum += v.x + v.y + v.z + v.w;
        }
        sum *= 0.0625f;
    }
    out[idx] = sum;
}

extern "C" void kernel_launch(void* const* d_in, const int* in_sizes, int n_in,
                              void* d_out, int out_size, void* d_ws, size_t ws_size,
                              hipStream_t stream) {
    const float* img = (const float*)d_in[0];
    float* out = (float*)d_out;
    // out_size = 32*160*3*16*16 = 3,932,160
    int total = NB * NTOK * NC * 16 * 16;
    int blocks = total / 256;  // 15360
    fovea_kernel<<<blocks, 256, 0, stream>>>(img, out);
}